// Round 14
// baseline (89.951 us; speedup 1.0000x reference)
//
#include <hip/hip_runtime.h>
#include <math.h>

#define NT_ 365
#define NS_ 1024
#define NH_ 64
#define NG_ 32
#define NW_ 514        // NH*8 + 2
#define CH_ 64         // timesteps per chunk (= wave size)
#define NCHUNK_ 6      // ceil(365/64); tail steps are harmless dummies
#define YPAD_ 65       // padded row stride: bank = (lane+j)%32, conflict-free R/W
#define SB_ 16         // sub-batch: met-dependent terms hoisted to registers

__device__ __forceinline__ float sigmoidf(float v) {
  return 1.0f / (1.0f + expf(-v));
}

// met = (Ps, Pl, relu(Ta), E); relu folded here since gm > 0
__device__ __forceinline__ float4 compute_met(float4 xv) {
  const float P = xv.x, E = xv.y, T1 = xv.z, T2 = xv.w;
  const float Ta = (T1 + T2) * 0.5f;
  float rP;
  if (T2 <= 0.0f) {
    rP = 0.0f;
  } else if (T1 >= 0.0f) {
    rP = 1.0f;
  } else {
    float r = (T1 + T2) / (T2 - T1);
    r = fminf(fmaxf(r, -0.999999f), 0.999999f);
    rP = 1.0f - acosf(r) * (1.0f / 3.1415f);
  }
  float4 m;
  m.x = (1.0f - rP) * P;   // Ps
  m.y = rP * P;            // Pl
  m.z = fmaxf(Ta, 0.0f);   // relu(Ta)
  m.w = E;
  return m;
}

// One wave per site (1024 waves = 1/SIMD machine-wide; sites==SIMDs, chains
// cannot be split across waves, and extra waves/SIMD measurably interfere:
// R5/R7/R12). The kernel is latency-bound on the recurrence's dependency
// cycle (~30 cyc/link for a lone wave). R14 change: addin joins through the
// S-branch (sa = Sm + addin, ready early), cutting the H-cycle from 7 to 6
// links: H0+sa -> max -> min -> *go -> sub -> min.
__global__ __launch_bounds__(256) void waternet_scan(
    const float* __restrict__ x,     // [NT, NS, 4]
    const float* __restrict__ xc,    // [NS, NG]
    const float* __restrict__ fc_w,  // [NW, NG]
    const float* __restrict__ fc_b,  // [NW]
    float* __restrict__ out)         // [NT, NS]
{
  __shared__ float4 smet[4][CH_];          // 4 KB:  [wave][step] met
  __shared__ float  ytile[4][CH_ * YPAD_]; // 66.6 KB: per-wave y rows

  const int tid  = threadIdx.x;
  const int lane = tid & 63;
  const int wv   = tid >> 6;
  const int site = (blockIdx.x << 2) + wv;
  const int us   = __builtin_amdgcn_readfirstlane(site);
  const float4* xp = (const float4*)x;

  // chunk-0 prefetch first: HBM latency hides under the gate GEMM
  float4 xcur = xp[lane * NS_ + site];  // t = lane

  // ---- prologue GEMM: w[site, j] = xc[site,:] . fc_w[j,:] + fc_b[j]
  float acc[8];
#pragma unroll
  for (int k = 0; k < 8; ++k) acc[k] = fc_b[k * NH_ + lane];
  float accq = fc_b[NW_ - 1];

  const float4* xcq = (const float4*)(xc + us * NG_);
  const float4* wq4 = (const float4*)fc_w;
#pragma unroll
  for (int g4 = 0; g4 < NG_ / 4; ++g4) {
    const float4 xv = xcq[g4];
#pragma unroll
    for (int k = 0; k < 8; ++k) {
      const float4 w = wq4[(k * NH_ + lane) * (NG_ / 4) + g4];
      acc[k] = fmaf(xv.x, w.x, acc[k]);
      acc[k] = fmaf(xv.y, w.y, acc[k]);
      acc[k] = fmaf(xv.z, w.z, acc[k]);
      acc[k] = fmaf(xv.w, w.w, acc[k]);
    }
    {
      const float4 w = wq4[(NW_ - 1) * (NG_ / 4) + g4];
      accq = fmaf(xv.x, w.x, accq);
      accq = fmaf(xv.y, w.y, accq);
      accq = fmaf(xv.z, w.z, accq);
      accq = fmaf(xv.w, w.w, accq);
    }
  }

  // ---- gates (per-lane = per hidden unit)
  const float gm = expf(acc[0]) + 1.0f;
  const float ge = sigmoidf(acc[1]) * 2.0f;
  const float go = sigmoidf(acc[2]);
  const float gl = expf(acc[3] * 2.0f);
  float mx = acc[4];
#pragma unroll
  for (int mm = 32; mm >= 1; mm >>= 1) mx = fmaxf(mx, __shfl_xor(mx, mm, 64));
  const float ex = expf(acc[4] - mx);
  float sm = ex;
#pragma unroll
  for (int mm = 32; mm >= 1; mm >>= 1) sm += __shfl_xor(sm, mm, 64);
  const float ga = ex / sm;
  const float gb = sigmoidf(acc[5]);
  const float kb = sigmoidf(acc[6]) * 0.1f;
  const float gi = sigmoidf(acc[7]);
  const float qb = fmaxf(accq, 0.0f) * (1.0f / NH_);
  const float kb1m = 1.0f - kb;                 // G0' = G*(1-kb)
  const float nge  = -ge;
  const float gq1  = go * (1.0f - gb) - 1.0f;   // y = ga*(H + M*gq1 + G*kb)

  // ---- scan state
  float S0 = 0.0f, H0 = 0.0f, G0 = 0.0f;

  // stage chunk-0 met (lane = step); per-wave slice + in-order DS -> no barrier
  smet[wv][lane] = compute_met(xcur);

  float*       yw = &ytile[wv][lane];          // step j writes yw[j*YPAD_]
  const float* yr = &ytile[wv][lane * YPAD_];  // reduce: lane sums its row

#pragma unroll 1   // keep body I-cache resident across the 6 iterations
  for (int c = 0; c < NCHUNK_; ++c) {
    // prefetch chunk c+1 from HBM (clamped dummy tail) — in flight all chunk
    int tn = (c + 1) * CH_ + lane;
    tn = (tn < NT_) ? tn : (NT_ - 1);
    const float4 xnext = xp[tn * NS_ + site];

    const float4* mp = &smet[wv][0];

#pragma unroll
    for (int sb = 0; sb < CH_ / SB_; ++sb) {
      // ---- phase 1: met-dependent terms, chain-independent burst ----------
      float melt[SB_], addin[SB_], Ps[SB_];
#pragma unroll
      for (int u = 0; u < SB_; ++u) {
        const float4 mt = mp[sb * SB_ + u];      // ds_read_b128, imm offset
        melt[u]  = mt.z * gm;                    // relu(Ta)*gm
        addin[u] = fmaf(mt.y, gi, mt.w * nge);   // Pl*gi - E*ge
        Ps[u]    = mt.x;
      }
      // ---- phase 2: recurrence; H-cycle = 6 links (addin folded via sa) ---
#pragma unroll
      for (int u = 0; u < SB_; ++u) {
        const float Sm = fminf(S0, melt[u]);     // S-branch, depth 1
        const float sa = Sm + addin[u];          // S-branch, depth 2 (early)
        S0 = (S0 - Sm) + Ps[u];                  // S-cycle closes at depth 3
        const float H  = fmaxf(H0 + sa, 0.0f);   // H-cycle: add(1) max(2)
        const float M  = fminf(H, gl);           // 3
        const float Q2a = M * go;                // 4
        H0 = fminf(H - Q2a, gl);                 // 5,6 -> next step
        const float G = fmaf(Q2a, gb, G0);       // G-branch (slack)
        G0 = G * kb1m;
        yw[(sb * SB_ + u) * YPAD_] =
            fmaf(G, kb, fmaf(M, gq1, H)) * ga;   // off-cycle ds_write_b32
      }
    }

    // ---- transposed reduction: lane t' sums row t' (bank=(t'+h)%32, free)
    float r0 = 0.0f, r1 = 0.0f, r2 = 0.0f, r3 = 0.0f;
#pragma unroll
    for (int h = 0; h < CH_; h += 4) {
      r0 += yr[h + 0];
      r1 += yr[h + 1];
      r2 += yr[h + 2];
      r3 += yr[h + 3];
    }
    const int t_out = c * CH_ + lane;
    if (t_out < NT_) out[t_out * NS_ + site] = ((r0 + r1) + (r2 + r3)) + qb;

    // stage next chunk's met (all reads above already issued; DS in-order)
    if (c + 1 < NCHUNK_) smet[wv][lane] = compute_met(xnext);
  }
}

extern "C" void kernel_launch(void* const* d_in, const int* in_sizes, int n_in,
                              void* d_out, int out_size, void* d_ws, size_t ws_size,
                              hipStream_t stream) {
  const float* x    = (const float*)d_in[0];
  const float* xc   = (const float*)d_in[1];
  const float* fc_w = (const float*)d_in[2];
  const float* fc_b = (const float*)d_in[3];
  float* out = (float*)d_out;

  // 1024 sites, one wave each; 4 waves/block -> 256 blocks, 1 wave/SIMD
  // across the full machine (sites == SIMDs: max spread, zero interference).
  hipLaunchKernelGGL(waternet_scan, dim3(NS_ / 4), dim3(256), 0, stream,
                     x, xc, fc_w, fc_b, out);
}